// Round 18
// baseline (160.289 us; speedup 1.0000x reference)
//
#include <hip/hip_runtime.h>
#include <cstdint>
#include <cstddef>

#define B_N   32768
#define C_N   1000
#define C_PAD 1024
#define D_N   256
#define K_N   16
#define ULB_N 50000
#define NCHUNK 128           // B_N / 256
#define CAP_L 128            // per-class sorted-list capacity

// output layout (floats): label[B], weight[B], topN[C*K], fidx[C*K], selected[ULB]
#define OFF_L 0
#define OFF_W 32768
#define OFF_T 65536
#define OFF_F 81536
#define OFF_S 97536

typedef __attribute__((ext_vector_type(8))) short short8;
typedef __attribute__((ext_vector_type(4))) float f32x4;

__device__ __forceinline__ unsigned ordf(float f) {
  unsigned u = __float_as_uint(f);
  return (u & 0x80000000u) ? ~u : (u | 0x80000000u);
}
__device__ __forceinline__ float iordf(unsigned h) {
  unsigned u = (h & 0x80000000u) ? (h & 0x7FFFFFFFu) : ~h;
  return __uint_as_float(u);
}
__device__ __forceinline__ unsigned short f2bf(float f) {   // RNE fp32 -> bf16
  unsigned u = __float_as_uint(f);
  return (unsigned short)((u + 0x7FFFu + ((u >> 16) & 1u)) >> 16);
}
__device__ __forceinline__ float bf2f(unsigned short h) {
  return __uint_as_float(((unsigned)h) << 16);
}

// ---- shared pack body: normalize 16 rows, split bf16 hi/lo, fragment-packed [hi|lo]
__device__ __forceinline__ void pack_body(const float* __restrict__ src,
                                          short8* __restrict__ dst,
                                          int mtL, int mt0, int nreal) {
  __shared__ float s[16][260];     // padded: only benign 2-way bank aliasing
  __shared__ float part[16][16];
  __shared__ float dv[16];
  const int t = threadIdx.x;
  const int r = t >> 4, c4 = (t & 15) * 4;
  const int grow = (mt0 + mtL) * 16 + r;
  #pragma unroll
  for (int i = 0; i < 4; ++i) {
    float4 v;
    if (grow < nreal) v = *reinterpret_cast<const float4*>(&src[(size_t)grow * D_N + c4 + 64 * i]);
    else { v.x = 0.f; v.y = 0.f; v.z = 0.f; v.w = 0.f; }
    s[r][c4 + 64 * i + 0] = v.x; s[r][c4 + 64 * i + 1] = v.y;
    s[r][c4 + 64 * i + 2] = v.z; s[r][c4 + 64 * i + 3] = v.w;
  }
  __syncthreads();
  {
    int c0 = t & 15;
    float ss = 0.f;
    #pragma unroll
    for (int j = 0; j < 16; ++j) { float x = s[r][c0 + 16 * j]; ss += x * x; }
    part[r][c0] = ss;
  }
  __syncthreads();
  if (t < 16) {
    float ss = 0.f;
    #pragma unroll
    for (int j = 0; j < 16; ++j) ss += part[t][j];
    dv[t] = 1.0f / fmaxf(sqrtf(ss), 1e-8f);
  }
  __syncthreads();
  #pragma unroll
  for (int i = 0; i < 4; ++i) {
    int p = t + 256 * i;            // 1024 fragment slots per 16-row tile
    int si = p >> 6, l = p & 63;
    int mr = l & 15, g = l >> 4;
    int kc = (si & 7) * 32 + g * 8;
    bool lo = si >= 8;
    float di = dv[mr];
    short8 v;
    #pragma unroll
    for (int j = 0; j < 8; ++j) {
      float q = s[mr][kc + j] * di;
      unsigned short hi = f2bf(q);
      unsigned short e = lo ? f2bf(q - bf2f(hi)) : hi;
      v[j] = (short)e;
    }
    dst[(size_t)mtL * 1024 + p] = v;
  }
  __syncthreads();   // safe reuse if called twice in one block
}

// merged front: workspace init + centroid pack (blocks < 64) + A-pack (all 2048
// blocks when packA). Grid = 2048 (covers init ranges: 524288 threads).
__global__ __launch_bounds__(256) void k_front(const float* __restrict__ cent,
                                               const float* __restrict__ feat,
                                               short8* __restrict__ Bp,
                                               short8* __restrict__ Ap,
                                               int packA,
                                               unsigned long long* keys, float* s1, float* s2,
                                               int* cnt, int* besti) {
  int i = blockIdx.x * blockDim.x + threadIdx.x;
  if (i < B_N)  keys[i] = 0ull;
  if (i < C_PAD) { s1[i] = 0.f; s2[i] = 0.f; cnt[i] = 0; }
  if (i < ULB_N) besti[i] = -1;
  if (blockIdx.x < 64) pack_body(cent, Bp, blockIdx.x, 0, C_N);
  if (packA) pack_body(feat, Ap, blockIdx.x, 0, B_N);
}

__global__ __launch_bounds__(256) void k_pack(const float* __restrict__ src,
                                              short8* __restrict__ dst,
                                              int mt0, int nreal) {
  pack_body(src, dst, blockIdx.x, mt0, nreal);
}

// standalone row-softmax scores (fallback path only)
__global__ __launch_bounds__(256) void k_scores(const float* __restrict__ pred,
                                                float* __restrict__ scores) {
  __shared__ float red[8];
  int r = blockIdx.x, t = threadIdx.x;
  const float* row = pred + (size_t)r * C_N;
  float4 v;
  bool act = t < 250;
  if (act) v = *reinterpret_cast<const float4*>(&row[t * 4]);
  else { v.x = -INFINITY; v.y = -INFINITY; v.z = -INFINITY; v.w = -INFINITY; }
  float m = fmaxf(fmaxf(v.x, v.y), fmaxf(v.z, v.w));
  #pragma unroll
  for (int mk = 1; mk < 64; mk <<= 1) m = fmaxf(m, __shfl_xor(m, mk, 64));
  int wid = t >> 6, lane = t & 63;
  if (lane == 0) red[wid] = m;
  __syncthreads();
  m = fmaxf(fmaxf(red[0], red[1]), fmaxf(red[2], red[3]));
  float s = act ? expf(v.x - m) + expf(v.y - m) + expf(v.z - m) + expf(v.w - m) : 0.f;
  #pragma unroll
  for (int mk = 1; mk < 64; mk <<= 1) s += __shfl_xor(s, mk, 64);
  __syncthreads();
  if (lane == 0) red[4 + wid] = s;
  __syncthreads();
  if (t == 0) {
    float S = ((red[4] + red[5]) + red[6]) + red[7];
    scores[r] = 1.0f / S;
  }
}

// Fragment-direct MFMA GEMM: 128x128 tile, 4 waves of 64x64 (4x4 frags of 16x16x32).
// Register double-buffer with sched_barrier(0) fences, __launch_bounds__(256,2)
// (best-measured config: 120 VGPR, no spill; 2-phase structural plateau).
// FUSED SCORES (doScores): the bx==0 block of each 128-row panel computes the panel's
// row-softmax scores in its epilogue — one row per wave, 64-lane shfl reduce. The
// 131 MB pred stream flows through the GEMM's 94%-idle memory system (m114 overlap).
// Per-accumulator MFMA order (HH,LH,HL; slices ascending) identical to prior rounds.
__global__ __launch_bounds__(256, 2) void k_mfma(const short8* __restrict__ Ap,
                                                 const short8* __restrict__ Bp,
                                                 const float* __restrict__ pred,
                                                 float* __restrict__ scores,
                                                 unsigned long long* __restrict__ keys,
                                                 int row0, int doScores) {
  const int bid = blockIdx.x;
  const int nby = gridDim.x >> 3;
  int byl, bx;
  if ((nby & 63) == 0) {
    int xcd = bid & 7, j = bid >> 3;      // per-XCD block index (round-robin dispatch)
    int slab = nby >> 3;                  // A-panels per XCD
    int grp = j >> 6, jj = j & 63;        // groups of 8 panels x 8 bx
    byl = xcd * slab + grp * 8 + (jj & 7);
    bx = jj >> 3;
  } else { byl = bid >> 3; bx = bid & 7; }

  const int w = threadIdx.x >> 6, l = threadIdx.x & 63;
  const int wm = (w & 1) * 64, wn = (w >> 1) * 64;
  const short8* a0 = Ap + (size_t)(byl * 8 + (wm >> 4)) * 1024 + l;
  const short8* b0 = Bp + (size_t)(bx * 8 + (wn >> 4)) * 1024 + l;

  f32x4 acc[4][4];
  #pragma unroll
  for (int i = 0; i < 4; ++i)
    #pragma unroll
    for (int j = 0; j < 4; ++j) { acc[i][j][0] = 0.f; acc[i][j][1] = 0.f; acc[i][j][2] = 0.f; acc[i][j][3] = 0.f; }

  short8 A0h[4], B0h[4], A0l[4], B0l[4];   // set 0
  short8 A1h[4], B1h[4], A1l[4], B1l[4];   // set 1
#define LOADSET(Xh, Yh, Xl, Yl, ks) { \
    _Pragma("unroll") \
    for (int i = 0; i < 4; ++i) Xh[i] = a0[(ks) * 64 + i * 1024]; \
    _Pragma("unroll") \
    for (int i = 0; i < 4; ++i) Yh[i] = b0[(ks) * 64 + i * 1024]; \
    _Pragma("unroll") \
    for (int i = 0; i < 4; ++i) Xl[i] = a0[((ks) + 8) * 64 + i * 1024]; \
    _Pragma("unroll") \
    for (int i = 0; i < 4; ++i) Yl[i] = b0[((ks) + 8) * 64 + i * 1024]; }
#define MFMA16(fa, fb) { \
    _Pragma("unroll") \
    for (int mi = 0; mi < 4; ++mi) \
      _Pragma("unroll") \
      for (int nj = 0; nj < 4; ++nj) \
        acc[mi][nj] = __builtin_amdgcn_mfma_f32_16x16x32_bf16(fa[mi], fb[nj], acc[mi][nj], 0, 0, 0); }
#define MFMA48(Xh, Yh, Xl, Yl) { MFMA16(Xh, Yh) MFMA16(Xl, Yh) MFMA16(Xh, Yl) }
#define FENCE __builtin_amdgcn_sched_barrier(0);

  LOADSET(A0h, B0h, A0l, B0l, 0)
  #pragma unroll 1
  for (int ks = 0; ks < 6; ks += 2) {
    LOADSET(A1h, B1h, A1l, B1l, ks + 1)      // prefetch next slice (issue NOW)
    FENCE
    MFMA48(A0h, B0h, A0l, B0l)               // compute current while loads fly
    FENCE
    LOADSET(A0h, B0h, A0l, B0l, ks + 2)
    FENCE
    MFMA48(A1h, B1h, A1l, B1l)
    FENCE
  }
  // peeled tail: slices 6 and 7
  LOADSET(A1h, B1h, A1l, B1l, 7)
  FENCE
  MFMA48(A0h, B0h, A0l, B0l)
  FENCE
  MFMA48(A1h, B1h, A1l, B1l)
#undef LOADSET
#undef MFMA16
#undef MFMA48
#undef FENCE

  // C/D layout: col = lane&15, row = (lane>>4)*4 + reg  [m89-verified]
  const int cb = bx * 128 + wn + (l & 15);
  #pragma unroll
  for (int mi = 0; mi < 4; ++mi) {
    #pragma unroll
    for (int r = 0; r < 4; ++r) {
      float bv = -INFINITY; int bc = 0x7FFFFFFF;
      #pragma unroll
      for (int nj = 0; nj < 4; ++nj) {
        int c = cb + nj * 16;
        float v = acc[mi][nj][r];
        if (c < C_N && v > bv) { bv = v; bc = c; }
      }
      #pragma unroll
      for (int mk = 1; mk < 16; mk <<= 1) {   // reduce the 16 lanes sharing (l>>4)
        float ov = __shfl_xor(bv, mk, 64);
        int oc = __shfl_xor(bc, mk, 64);
        if (ov > bv || (ov == bv && oc < bc)) { bv = ov; bc = oc; }
      }
      if ((l & 15) == 0) {
        unsigned long long kk =
            (((unsigned long long)ordf(bv)) << 32) |
            (unsigned long long)(0xFFFFFFFFu - (unsigned)bc);
        atomicMax(&keys[row0 + byl * 128 + wm + mi * 16 + (l >> 4) * 4 + r], kk);
      }
    }
  }

  // fused scores: one block per panel (bx==0), one row per wave, 32 rows/wave
  if (doScores && bx == 0) {
    const int rbase = row0 + byl * 128;
    for (int rr = w; rr < 128; rr += 4) {
      const float* row = pred + (size_t)(rbase + rr) * C_N;
      float4 v[4];
      float mx = -INFINITY;
      #pragma unroll
      for (int j = 0; j < 4; ++j) {
        int p = l + 64 * j;
        if (p < 250) v[j] = *reinterpret_cast<const float4*>(&row[p * 4]);
        else { v[j].x = -INFINITY; v[j].y = -INFINITY; v[j].z = -INFINITY; v[j].w = -INFINITY; }
        mx = fmaxf(mx, fmaxf(fmaxf(v[j].x, v[j].y), fmaxf(v[j].z, v[j].w)));
      }
      #pragma unroll
      for (int mk = 1; mk < 64; mk <<= 1) mx = fmaxf(mx, __shfl_xor(mx, mk, 64));
      float s = 0.f;
      #pragma unroll
      for (int j = 0; j < 4; ++j) {
        if (l + 64 * j < 250)
          s += expf(v[j].x - mx) + expf(v[j].y - mx) + expf(v[j].z - mx) + expf(v[j].w - mx);
      }
      #pragma unroll
      for (int mk = 1; mk < 64; mk <<= 1) s += __shfl_xor(s, mk, 64);
      if (l == 0) scores[rbase + rr] = 1.0f / s;
    }
  }
}

// merged: decode keys -> labels/cosf/out, class stats atomics, besti,
//         per-chunk class histogram + within-chunk stable rank
__global__ __launch_bounds__(256) void k_post(const unsigned long long* __restrict__ keys,
                                              const int* __restrict__ ui,
                                              int* __restrict__ labels, float* __restrict__ cosf_,
                                              float* __restrict__ s1, float* __restrict__ s2,
                                              int* __restrict__ cnt, int* __restrict__ besti,
                                              unsigned short* __restrict__ lrank,
                                              unsigned short* __restrict__ hist,
                                              float* __restrict__ out) {
  __shared__ int lab[256];
  __shared__ unsigned histl[C_PAD];
  int chunk = blockIdx.x, t = threadIdx.x;
  int b = chunk * 256 + t;
  #pragma unroll
  for (int r = 0; r < 4; ++r) histl[t + 256 * r] = 0;
  unsigned long long k = keys[b];
  int c = (int)(0xFFFFFFFFu - (unsigned)k);
  float f = iordf((unsigned)(k >> 32));
  labels[b] = c;
  cosf_[b] = f;
  out[OFF_L + b] = (float)c;
  atomicAdd(&s1[c], f);
  atomicAdd(&s2[c], f * f);
  atomicAdd(&cnt[c], 1);
  atomicMax(&besti[ui[b]], b);   // last-write-wins => largest sample index
  lab[t] = c;
  __syncthreads();
  atomicAdd(&histl[c], 1u);
  unsigned rk = 0;
  for (int j = 0; j < t; ++j) rk += (lab[j] == c);
  lrank[b] = (unsigned short)rk;
  __syncthreads();
  #pragma unroll
  for (int r = 0; r < 4; ++r)
    hist[chunk * C_PAD + t + 256 * r] = (unsigned short)histl[t + 256 * r];
}

// per-class exclusive prefix over chunks — wave-parallel (one wave per class)
__global__ __launch_bounds__(256) void k_prefix(const unsigned short* __restrict__ hist,
                                                unsigned short* __restrict__ base,
                                                int* __restrict__ class_n) {
  int c = blockIdx.x * 4 + (threadIdx.x >> 6);   // 256 blocks x 4 waves = 1024 classes
  int l = threadIdx.x & 63;
  unsigned h0 = hist[(2 * l) * C_PAD + c];
  unsigned h1 = hist[(2 * l + 1) * C_PAD + c];
  unsigned pair = h0 + h1;
  unsigned s = pair;
  #pragma unroll
  for (int off = 1; off < 64; off <<= 1) {
    unsigned v = __shfl_up(s, off, 64);
    if (l >= off) s += v;
  }
  unsigned excl = s - pair;                       // exclusive prefix of chunk 2l
  base[(2 * l) * C_PAD + c] = (unsigned short)excl;
  base[(2 * l + 1) * C_PAD + c] = (unsigned short)(excl + h0);
  if (l == 63) class_n[c] = (int)s;
}

// merged: scatter score/ui into pre-sorted per-class lists + weight + selected_label
__global__ __launch_bounds__(256) void k_sw(const int* __restrict__ labels,
                                            const unsigned short* __restrict__ lrank,
                                            const unsigned short* __restrict__ base,
                                            const float* __restrict__ scores,
                                            const int* __restrict__ ui,
                                            const float* __restrict__ cosf_,
                                            const float* __restrict__ s1,
                                            const float* __restrict__ s2,
                                            const int* __restrict__ cnt,
                                            const int* __restrict__ besti,
                                            float* __restrict__ lists_s,
                                            int* __restrict__ lists_u,
                                            float* __restrict__ out) {
  int b = blockIdx.x * blockDim.x + threadIdx.x;
  if (b >= B_N) return;
  int c = labels[b];
  int chunk = b >> 8;
  int pos = (int)base[chunk * C_PAD + c] + (int)lrank[b];
  if (pos < CAP_L) {
    lists_s[c * CAP_L + pos] = scores[b];
    lists_u[c * CAP_L + pos] = ui[b];
  }
  float n = (float)cnt[c];
  float m = s1[c] / fmaxf(n, 1.0f);
  float var = (s2[c] - n * m * m) / fmaxf(n - 1.0f, 1.0f);
  float sd = sqrtf(fmaxf(var, 0.0f) + 1e-12f);
  float cf = cosf_[b];
  float wgt = 1.0f;
  if (cf < m) {
    float z = (cf - m) / sd;
    const float inv = 0.3989422804014327f;
    wgt = expf(-0.5f * (z * z)) * inv / sd;
  }
  out[OFF_W + b] = wgt;
  // selected_label: thread covers p=b and p=b+32768
  {
    int bi = besti[b];
    out[OFF_S + b] = (bi < 0) ? -1.0f : (float)labels[bi];
  }
  int p2 = b + B_N;
  if (p2 < ULB_N) {
    int bi = besti[p2];
    out[OFF_S + p2] = (bi < 0) ? -1.0f : (float)labels[bi];
  }
}

// one wave per class: parallel 64-wide gather of the pre-sorted list,
// serial top-16 replay via shfl broadcast (all lanes replicate state).
__global__ __launch_bounds__(256) void k_replay(const float* __restrict__ ptn,
                                                const float* __restrict__ lists_s,
                                                const int* __restrict__ lists_u,
                                                const int* __restrict__ class_n,
                                                const int* __restrict__ labels,
                                                const float* __restrict__ scores,
                                                const int* __restrict__ ui,
                                                float* __restrict__ out) {
  int c = blockIdx.x * 4 + (threadIdx.x >> 6);
  int lane = threadIdx.x & 63;
  if (c >= C_N) return;

  float tv[K_N]; int fi[K_N];
  #pragma unroll
  for (int j = 0; j < K_N; ++j) { tv[j] = ptn[c * K_N + j]; fi[j] = -1; }

  auto ins = [&](float s, int u) {
    float mv = tv[0]; int mi = 0;
    #pragma unroll
    for (int j = 1; j < K_N; ++j) { if (tv[j] < mv) { mv = tv[j]; mi = j; } }  // first-min
    if (s > mv) {
      #pragma unroll
      for (int j = 0; j < K_N; ++j) { if (j == mi) { tv[j] = s; fi[j] = u; } }
    }
  };

  int n = class_n[c];
  if (n <= CAP_L) {
    for (int t0 = 0; t0 < n; t0 += 64) {
      float s = 0.f; int u = 0;
      int idx = t0 + lane;
      if (idx < n) { s = lists_s[c * CAP_L + idx]; u = lists_u[c * CAP_L + idx]; }
      int lim = min(64, n - t0);
      for (int t = 0; t < lim; ++t) {
        float ss = __shfl(s, t, 64);
        int uu = __shfl(u, t, 64);
        ins(ss, uu);
      }
    }
  } else {
    // cooperative fallback (practically unreachable): scan all samples in order
    for (int t0 = 0; t0 < B_N; t0 += 64) {
      int lb = labels[t0 + lane];
      unsigned long long match = __ballot(lb == c);
      while (match) {
        int t = __ffsll((long long)match) - 1;
        match &= match - 1;
        int b = t0 + t;
        ins(scores[b], ui[b]);
      }
    }
  }

  if (lane == 0) {
    #pragma unroll
    for (int j = 0; j < K_N; ++j) {
      out[OFF_T + c * K_N + j] = tv[j];
      out[OFF_F + c * K_N + j] = (float)fi[j];
    }
  }
}

extern "C" void kernel_launch(void* const* d_in, const int* in_sizes, int n_in,
                              void* d_out, int out_size, void* d_ws, size_t ws_size,
                              hipStream_t stream) {
  const float* feat = (const float*)d_in[0];
  const float* pred = (const float*)d_in[1];
  const float* cent = (const float*)d_in[2];
  const float* ptn  = (const float*)d_in[3];
  const int*   ui   = (const int*)d_in[4];
  float* out = (float*)d_out;
  char* ws = (char*)d_ws;

  size_t o = 0;
  auto alloc = [&](size_t bytes) { void* p = ws + o; o += (bytes + 255) & ~size_t(255); return p; };
  short8* Bp                = (short8*)alloc(64 * 1024 * 16);        // 1.05 MB packed B' [hi|lo]
  unsigned long long* keys  = (unsigned long long*)alloc(B_N * 8);
  int*   labels             = (int*)  alloc(B_N * 4);
  float* scores             = (float*)alloc(B_N * 4);
  float* cosf_              = (float*)alloc(B_N * 4);
  float* s1                 = (float*)alloc(C_PAD * 4);
  float* s2                 = (float*)alloc(C_PAD * 4);
  int*   cnt                = (int*)  alloc(C_PAD * 4);
  int*   besti              = (int*)  alloc(ULB_N * 4);
  unsigned short* lrank     = (unsigned short*)alloc(B_N * 2);
  unsigned short* hist      = (unsigned short*)alloc(NCHUNK * C_PAD * 2);
  unsigned short* base      = (unsigned short*)alloc(NCHUNK * C_PAD * 2);
  int*   class_n            = (int*)  alloc(C_PAD * 4);
  float* lists_s            = (float*)alloc(C_N * CAP_L * 4);
  int*   lists_u            = (int*)  alloc(C_N * CAP_L * 4);

  // A' chunk region: 131072 B per 128-row group (8 m-tiles x 1024 frags x 16 B)
  size_t avail = (ws_size > o) ? ws_size - o : 0;
  int g128 = (int)(avail / 131072ull);
  if (g128 < 1) g128 = 1;
  if (g128 > 256) g128 = 256;
  if (g128 >= 64) g128 &= ~63;          // keep swizzle-eligible chunks
  else if (g128 >= 8) g128 &= ~7;
  short8* Achunk = (short8*)(ws + o);
  int fullA = (g128 >= 256) ? 1 : 0;

  k_front    <<<2048, 256, 0, stream>>>(cent, feat, Bp, Achunk, fullA, keys, s1, s2, cnt, besti);
  if (fullA) {
    k_mfma   <<<2048, 256, 0, stream>>>(Achunk, Bp, pred, scores, keys, 0, 1);
  } else {
    k_scores <<<B_N, 256, 0, stream>>>(pred, scores);
    for (int c0 = 0; c0 < 256; c0 += g128) {
      int g = (g128 < 256 - c0) ? g128 : (256 - c0);
      k_pack <<<g * 8, 256, 0, stream>>>(feat, Achunk, c0 * 8, B_N);
      k_mfma <<<g * 8, 256, 0, stream>>>(Achunk, Bp, pred, scores, keys, c0 * 128, 0);
    }
  }
  k_post     <<<NCHUNK, 256, 0, stream>>>(keys, ui, labels, cosf_, s1, s2, cnt, besti, lrank, hist, out);
  k_prefix   <<<256, 256, 0, stream>>>(hist, base, class_n);
  k_sw       <<<B_N / 256, 256, 0, stream>>>(labels, lrank, base, scores, ui, cosf_, s1, s2, cnt, besti, lists_s, lists_u, out);
  k_replay   <<<250, 256, 0, stream>>>(ptn, lists_s, lists_u, class_n, labels, scores, ui, out);
}

// Round 19
// 147.925 us; speedup vs baseline: 1.0836x; 1.0836x over previous
//
#include <hip/hip_runtime.h>
#include <cstdint>
#include <cstddef>

#define B_N   32768
#define C_N   1000
#define C_PAD 1024
#define D_N   256
#define K_N   16
#define ULB_N 50000
#define NCHUNK 128           // B_N / 256
#define CAP_L 128            // per-class sorted-list capacity

// output layout (floats): label[B], weight[B], topN[C*K], fidx[C*K], selected[ULB]
#define OFF_L 0
#define OFF_W 32768
#define OFF_T 65536
#define OFF_F 81536
#define OFF_S 97536

typedef __attribute__((ext_vector_type(8))) short short8;
typedef __attribute__((ext_vector_type(4))) float f32x4;

__device__ __forceinline__ unsigned ordf(float f) {
  unsigned u = __float_as_uint(f);
  return (u & 0x80000000u) ? ~u : (u | 0x80000000u);
}
__device__ __forceinline__ float iordf(unsigned h) {
  unsigned u = (h & 0x80000000u) ? (h & 0x7FFFFFFFu) : ~h;
  return __uint_as_float(u);
}
__device__ __forceinline__ unsigned short f2bf(float f) {   // RNE fp32 -> bf16
  unsigned u = __float_as_uint(f);
  return (unsigned short)((u + 0x7FFFu + ((u >> 16) & 1u)) >> 16);
}
__device__ __forceinline__ float bf2f(unsigned short h) {
  return __uint_as_float(((unsigned)h) << 16);
}

// ---- shared pack body: normalize 16 rows, split bf16 hi/lo, fragment-packed [hi|lo]
__device__ __forceinline__ void pack_body(const float* __restrict__ src,
                                          short8* __restrict__ dst,
                                          int mtL, int mt0, int nreal) {
  __shared__ float s[16][260];     // padded: only benign 2-way bank aliasing
  __shared__ float part[16][16];
  __shared__ float dv[16];
  const int t = threadIdx.x;
  const int r = t >> 4, c4 = (t & 15) * 4;
  const int grow = (mt0 + mtL) * 16 + r;
  #pragma unroll
  for (int i = 0; i < 4; ++i) {
    float4 v;
    if (grow < nreal) v = *reinterpret_cast<const float4*>(&src[(size_t)grow * D_N + c4 + 64 * i]);
    else { v.x = 0.f; v.y = 0.f; v.z = 0.f; v.w = 0.f; }
    s[r][c4 + 64 * i + 0] = v.x; s[r][c4 + 64 * i + 1] = v.y;
    s[r][c4 + 64 * i + 2] = v.z; s[r][c4 + 64 * i + 3] = v.w;
  }
  __syncthreads();
  {
    int c0 = t & 15;
    float ss = 0.f;
    #pragma unroll
    for (int j = 0; j < 16; ++j) { float x = s[r][c0 + 16 * j]; ss += x * x; }
    part[r][c0] = ss;
  }
  __syncthreads();
  if (t < 16) {
    float ss = 0.f;
    #pragma unroll
    for (int j = 0; j < 16; ++j) ss += part[t][j];
    dv[t] = 1.0f / fmaxf(sqrtf(ss), 1e-8f);
  }
  __syncthreads();
  #pragma unroll
  for (int i = 0; i < 4; ++i) {
    int p = t + 256 * i;            // 1024 fragment slots per 16-row tile
    int si = p >> 6, l = p & 63;
    int mr = l & 15, g = l >> 4;
    int kc = (si & 7) * 32 + g * 8;
    bool lo = si >= 8;
    float di = dv[mr];
    short8 v;
    #pragma unroll
    for (int j = 0; j < 8; ++j) {
      float q = s[mr][kc + j] * di;
      unsigned short hi = f2bf(q);
      unsigned short e = lo ? f2bf(q - bf2f(hi)) : hi;
      v[j] = (short)e;
    }
    dst[(size_t)mtL * 1024 + p] = v;
  }
  __syncthreads();   // safe reuse if called twice in one block
}

// merged front: workspace init + centroid pack (blocks < 64) + A-pack (blocks < 2048
// when packA) + row-softmax scores (ALL blocks; grid = B_N rows).
__global__ __launch_bounds__(256) void k_front(const float* __restrict__ cent,
                                               const float* __restrict__ pred,
                                               const float* __restrict__ feat,
                                               short8* __restrict__ Bp,
                                               short8* __restrict__ Ap,
                                               int packA,
                                               float* __restrict__ scores,
                                               unsigned long long* keys, float* s1, float* s2,
                                               int* cnt, int* besti) {
  __shared__ float red[8];
  int i = blockIdx.x * blockDim.x + threadIdx.x;
  if (i < B_N)  keys[i] = 0ull;
  if (i < C_PAD) { s1[i] = 0.f; s2[i] = 0.f; cnt[i] = 0; }
  if (i < ULB_N) besti[i] = -1;
  if (blockIdx.x < 64) pack_body(cent, Bp, blockIdx.x, 0, C_N);
  if (packA && blockIdx.x < 2048) pack_body(feat, Ap, blockIdx.x, 0, B_N);

  // scores: one row per block
  int r = blockIdx.x, t = threadIdx.x;
  const float* row = pred + (size_t)r * C_N;
  float4 v;
  bool act = t < 250;
  if (act) v = *reinterpret_cast<const float4*>(&row[t * 4]);
  else { v.x = -INFINITY; v.y = -INFINITY; v.z = -INFINITY; v.w = -INFINITY; }
  float m = fmaxf(fmaxf(v.x, v.y), fmaxf(v.z, v.w));
  #pragma unroll
  for (int mk = 1; mk < 64; mk <<= 1) m = fmaxf(m, __shfl_xor(m, mk, 64));
  int wid = t >> 6, lane = t & 63;
  if (lane == 0) red[wid] = m;
  __syncthreads();
  m = fmaxf(fmaxf(red[0], red[1]), fmaxf(red[2], red[3]));
  float s = act ? expf(v.x - m) + expf(v.y - m) + expf(v.z - m) + expf(v.w - m) : 0.f;
  #pragma unroll
  for (int mk = 1; mk < 64; mk <<= 1) s += __shfl_xor(s, mk, 64);
  __syncthreads();
  if (lane == 0) red[4 + wid] = s;
  __syncthreads();
  if (t == 0) {
    float S = ((red[4] + red[5]) + red[6]) + red[7];
    scores[r] = 1.0f / S;
  }
}

__global__ __launch_bounds__(256) void k_pack(const float* __restrict__ src,
                                              short8* __restrict__ dst,
                                              int mt0, int nreal) {
  pack_body(src, dst, blockIdx.x, mt0, nreal);
}

// Fragment-direct MFMA GEMM: 128x128 tile, 4 waves of 64x64 (4x4 frags of 16x16x32).
// Register double-buffer with sched_barrier(0) fences, __launch_bounds__(256,2)
// (best-measured config: 120 VGPR, no spill, 77 us; 2-phase structural plateau).
// Per-accumulator MFMA order (HH,LH,HL; slices ascending) identical to prior rounds.
__global__ __launch_bounds__(256, 2) void k_mfma(const short8* __restrict__ Ap,
                                                 const short8* __restrict__ Bp,
                                                 unsigned long long* __restrict__ keys,
                                                 int row0) {
  const int bid = blockIdx.x;
  const int nby = gridDim.x >> 3;
  int byl, bx;
  if ((nby & 63) == 0) {
    int xcd = bid & 7, j = bid >> 3;      // per-XCD block index (round-robin dispatch)
    int slab = nby >> 3;                  // A-panels per XCD
    int grp = j >> 6, jj = j & 63;        // groups of 8 panels x 8 bx
    byl = xcd * slab + grp * 8 + (jj & 7);
    bx = jj >> 3;
  } else { byl = bid >> 3; bx = bid & 7; }

  const int w = threadIdx.x >> 6, l = threadIdx.x & 63;
  const int wm = (w & 1) * 64, wn = (w >> 1) * 64;
  const short8* a0 = Ap + (size_t)(byl * 8 + (wm >> 4)) * 1024 + l;
  const short8* b0 = Bp + (size_t)(bx * 8 + (wn >> 4)) * 1024 + l;

  f32x4 acc[4][4];
  #pragma unroll
  for (int i = 0; i < 4; ++i)
    #pragma unroll
    for (int j = 0; j < 4; ++j) { acc[i][j][0] = 0.f; acc[i][j][1] = 0.f; acc[i][j][2] = 0.f; acc[i][j][3] = 0.f; }

  short8 A0h[4], B0h[4], A0l[4], B0l[4];   // set 0
  short8 A1h[4], B1h[4], A1l[4], B1l[4];   // set 1
#define LOADSET(Xh, Yh, Xl, Yl, ks) { \
    _Pragma("unroll") \
    for (int i = 0; i < 4; ++i) Xh[i] = a0[(ks) * 64 + i * 1024]; \
    _Pragma("unroll") \
    for (int i = 0; i < 4; ++i) Yh[i] = b0[(ks) * 64 + i * 1024]; \
    _Pragma("unroll") \
    for (int i = 0; i < 4; ++i) Xl[i] = a0[((ks) + 8) * 64 + i * 1024]; \
    _Pragma("unroll") \
    for (int i = 0; i < 4; ++i) Yl[i] = b0[((ks) + 8) * 64 + i * 1024]; }
#define MFMA16(fa, fb) { \
    _Pragma("unroll") \
    for (int mi = 0; mi < 4; ++mi) \
      _Pragma("unroll") \
      for (int nj = 0; nj < 4; ++nj) \
        acc[mi][nj] = __builtin_amdgcn_mfma_f32_16x16x32_bf16(fa[mi], fb[nj], acc[mi][nj], 0, 0, 0); }
#define MFMA48(Xh, Yh, Xl, Yl) { MFMA16(Xh, Yh) MFMA16(Xl, Yh) MFMA16(Xh, Yl) }
#define FENCE __builtin_amdgcn_sched_barrier(0);

  LOADSET(A0h, B0h, A0l, B0l, 0)
  #pragma unroll 1
  for (int ks = 0; ks < 6; ks += 2) {
    LOADSET(A1h, B1h, A1l, B1l, ks + 1)      // prefetch next slice (issue NOW)
    FENCE
    MFMA48(A0h, B0h, A0l, B0l)               // compute current while loads fly
    FENCE
    LOADSET(A0h, B0h, A0l, B0l, ks + 2)
    FENCE
    MFMA48(A1h, B1h, A1l, B1l)
    FENCE
  }
  // peeled tail: slices 6 and 7
  LOADSET(A1h, B1h, A1l, B1l, 7)
  FENCE
  MFMA48(A0h, B0h, A0l, B0l)
  FENCE
  MFMA48(A1h, B1h, A1l, B1l)
#undef LOADSET
#undef MFMA16
#undef MFMA48
#undef FENCE

  // C/D layout: col = lane&15, row = (lane>>4)*4 + reg  [m89-verified]
  const int cb = bx * 128 + wn + (l & 15);
  #pragma unroll
  for (int mi = 0; mi < 4; ++mi) {
    #pragma unroll
    for (int r = 0; r < 4; ++r) {
      float bv = -INFINITY; int bc = 0x7FFFFFFF;
      #pragma unroll
      for (int nj = 0; nj < 4; ++nj) {
        int c = cb + nj * 16;
        float v = acc[mi][nj][r];
        if (c < C_N && v > bv) { bv = v; bc = c; }
      }
      #pragma unroll
      for (int mk = 1; mk < 16; mk <<= 1) {   // reduce the 16 lanes sharing (l>>4)
        float ov = __shfl_xor(bv, mk, 64);
        int oc = __shfl_xor(bc, mk, 64);
        if (ov > bv || (ov == bv && oc < bc)) { bv = ov; bc = oc; }
      }
      if ((l & 15) == 0) {
        unsigned long long kk =
            (((unsigned long long)ordf(bv)) << 32) |
            (unsigned long long)(0xFFFFFFFFu - (unsigned)bc);
        atomicMax(&keys[row0 + byl * 128 + wm + mi * 16 + (l >> 4) * 4 + r], kk);
      }
    }
  }
}

// merged: decode keys -> labels/cosf/out, class stats atomics, besti,
//         per-chunk class histogram + within-chunk stable rank
__global__ __launch_bounds__(256) void k_post(const unsigned long long* __restrict__ keys,
                                              const int* __restrict__ ui,
                                              int* __restrict__ labels, float* __restrict__ cosf_,
                                              float* __restrict__ s1, float* __restrict__ s2,
                                              int* __restrict__ cnt, int* __restrict__ besti,
                                              unsigned short* __restrict__ lrank,
                                              unsigned short* __restrict__ hist,
                                              float* __restrict__ out) {
  __shared__ int lab[256];
  __shared__ unsigned histl[C_PAD];
  int chunk = blockIdx.x, t = threadIdx.x;
  int b = chunk * 256 + t;
  #pragma unroll
  for (int r = 0; r < 4; ++r) histl[t + 256 * r] = 0;
  unsigned long long k = keys[b];
  int c = (int)(0xFFFFFFFFu - (unsigned)k);
  float f = iordf((unsigned)(k >> 32));
  labels[b] = c;
  cosf_[b] = f;
  out[OFF_L + b] = (float)c;
  atomicAdd(&s1[c], f);
  atomicAdd(&s2[c], f * f);
  atomicAdd(&cnt[c], 1);
  atomicMax(&besti[ui[b]], b);   // last-write-wins => largest sample index
  lab[t] = c;
  __syncthreads();
  atomicAdd(&histl[c], 1u);
  unsigned rk = 0;
  for (int j = 0; j < t; ++j) rk += (lab[j] == c);
  lrank[b] = (unsigned short)rk;
  __syncthreads();
  #pragma unroll
  for (int r = 0; r < 4; ++r)
    hist[chunk * C_PAD + t + 256 * r] = (unsigned short)histl[t + 256 * r];
}

// per-class exclusive prefix over chunks — wave-parallel (one wave per class)
__global__ __launch_bounds__(256) void k_prefix(const unsigned short* __restrict__ hist,
                                                unsigned short* __restrict__ base,
                                                int* __restrict__ class_n) {
  int c = blockIdx.x * 4 + (threadIdx.x >> 6);   // 256 blocks x 4 waves = 1024 classes
  int l = threadIdx.x & 63;
  unsigned h0 = hist[(2 * l) * C_PAD + c];
  unsigned h1 = hist[(2 * l + 1) * C_PAD + c];
  unsigned pair = h0 + h1;
  unsigned s = pair;
  #pragma unroll
  for (int off = 1; off < 64; off <<= 1) {
    unsigned v = __shfl_up(s, off, 64);
    if (l >= off) s += v;
  }
  unsigned excl = s - pair;                       // exclusive prefix of chunk 2l
  base[(2 * l) * C_PAD + c] = (unsigned short)excl;
  base[(2 * l + 1) * C_PAD + c] = (unsigned short)(excl + h0);
  if (l == 63) class_n[c] = (int)s;
}

// merged: scatter score/ui into pre-sorted per-class lists + weight + selected_label
__global__ __launch_bounds__(256) void k_sw(const int* __restrict__ labels,
                                            const unsigned short* __restrict__ lrank,
                                            const unsigned short* __restrict__ base,
                                            const float* __restrict__ scores,
                                            const int* __restrict__ ui,
                                            const float* __restrict__ cosf_,
                                            const float* __restrict__ s1,
                                            const float* __restrict__ s2,
                                            const int* __restrict__ cnt,
                                            const int* __restrict__ besti,
                                            float* __restrict__ lists_s,
                                            int* __restrict__ lists_u,
                                            float* __restrict__ out) {
  int b = blockIdx.x * blockDim.x + threadIdx.x;
  if (b >= B_N) return;
  int c = labels[b];
  int chunk = b >> 8;
  int pos = (int)base[chunk * C_PAD + c] + (int)lrank[b];
  if (pos < CAP_L) {
    lists_s[c * CAP_L + pos] = scores[b];
    lists_u[c * CAP_L + pos] = ui[b];
  }
  float n = (float)cnt[c];
  float m = s1[c] / fmaxf(n, 1.0f);
  float var = (s2[c] - n * m * m) / fmaxf(n - 1.0f, 1.0f);
  float sd = sqrtf(fmaxf(var, 0.0f) + 1e-12f);
  float cf = cosf_[b];
  float wgt = 1.0f;
  if (cf < m) {
    float z = (cf - m) / sd;
    const float inv = 0.3989422804014327f;
    wgt = expf(-0.5f * (z * z)) * inv / sd;
  }
  out[OFF_W + b] = wgt;
  // selected_label: thread covers p=b and p=b+32768
  {
    int bi = besti[b];
    out[OFF_S + b] = (bi < 0) ? -1.0f : (float)labels[bi];
  }
  int p2 = b + B_N;
  if (p2 < ULB_N) {
    int bi = besti[p2];
    out[OFF_S + p2] = (bi < 0) ? -1.0f : (float)labels[bi];
  }
}

// one wave per class: parallel 64-wide gather of the pre-sorted list,
// serial top-16 replay via shfl broadcast (all lanes replicate state).
__global__ __launch_bounds__(256) void k_replay(const float* __restrict__ ptn,
                                                const float* __restrict__ lists_s,
                                                const int* __restrict__ lists_u,
                                                const int* __restrict__ class_n,
                                                const int* __restrict__ labels,
                                                const float* __restrict__ scores,
                                                const int* __restrict__ ui,
                                                float* __restrict__ out) {
  int c = blockIdx.x * 4 + (threadIdx.x >> 6);
  int lane = threadIdx.x & 63;
  if (c >= C_N) return;

  float tv[K_N]; int fi[K_N];
  #pragma unroll
  for (int j = 0; j < K_N; ++j) { tv[j] = ptn[c * K_N + j]; fi[j] = -1; }

  auto ins = [&](float s, int u) {
    float mv = tv[0]; int mi = 0;
    #pragma unroll
    for (int j = 1; j < K_N; ++j) { if (tv[j] < mv) { mv = tv[j]; mi = j; } }  // first-min
    if (s > mv) {
      #pragma unroll
      for (int j = 0; j < K_N; ++j) { if (j == mi) { tv[j] = s; fi[j] = u; } }
    }
  };

  int n = class_n[c];
  if (n <= CAP_L) {
    for (int t0 = 0; t0 < n; t0 += 64) {
      float s = 0.f; int u = 0;
      int idx = t0 + lane;
      if (idx < n) { s = lists_s[c * CAP_L + idx]; u = lists_u[c * CAP_L + idx]; }
      int lim = min(64, n - t0);
      for (int t = 0; t < lim; ++t) {
        float ss = __shfl(s, t, 64);
        int uu = __shfl(u, t, 64);
        ins(ss, uu);
      }
    }
  } else {
    // cooperative fallback (practically unreachable): scan all samples in order
    for (int t0 = 0; t0 < B_N; t0 += 64) {
      int lb = labels[t0 + lane];
      unsigned long long match = __ballot(lb == c);
      while (match) {
        int t = __ffsll((long long)match) - 1;
        match &= match - 1;
        int b = t0 + t;
        ins(scores[b], ui[b]);
      }
    }
  }

  if (lane == 0) {
    #pragma unroll
    for (int j = 0; j < K_N; ++j) {
      out[OFF_T + c * K_N + j] = tv[j];
      out[OFF_F + c * K_N + j] = (float)fi[j];
    }
  }
}

extern "C" void kernel_launch(void* const* d_in, const int* in_sizes, int n_in,
                              void* d_out, int out_size, void* d_ws, size_t ws_size,
                              hipStream_t stream) {
  const float* feat = (const float*)d_in[0];
  const float* pred = (const float*)d_in[1];
  const float* cent = (const float*)d_in[2];
  const float* ptn  = (const float*)d_in[3];
  const int*   ui   = (const int*)d_in[4];
  float* out = (float*)d_out;
  char* ws = (char*)d_ws;

  size_t o = 0;
  auto alloc = [&](size_t bytes) { void* p = ws + o; o += (bytes + 255) & ~size_t(255); return p; };
  short8* Bp                = (short8*)alloc(64 * 1024 * 16);        // 1.05 MB packed B' [hi|lo]
  unsigned long long* keys  = (unsigned long long*)alloc(B_N * 8);
  int*   labels             = (int*)  alloc(B_N * 4);
  float* scores             = (float*)alloc(B_N * 4);
  float* cosf_              = (float*)alloc(B_N * 4);
  float* s1                 = (float*)alloc(C_PAD * 4);
  float* s2                 = (float*)alloc(C_PAD * 4);
  int*   cnt                = (int*)  alloc(C_PAD * 4);
  int*   besti              = (int*)  alloc(ULB_N * 4);
  unsigned short* lrank     = (unsigned short*)alloc(B_N * 2);
  unsigned short* hist      = (unsigned short*)alloc(NCHUNK * C_PAD * 2);
  unsigned short* base      = (unsigned short*)alloc(NCHUNK * C_PAD * 2);
  int*   class_n            = (int*)  alloc(C_PAD * 4);
  float* lists_s            = (float*)alloc(C_N * CAP_L * 4);
  int*   lists_u            = (int*)  alloc(C_N * CAP_L * 4);

  // A' chunk region: 131072 B per 128-row group (8 m-tiles x 1024 frags x 16 B)
  size_t avail = (ws_size > o) ? ws_size - o : 0;
  int g128 = (int)(avail / 131072ull);
  if (g128 < 1) g128 = 1;
  if (g128 > 256) g128 = 256;
  if (g128 >= 64) g128 &= ~63;          // keep swizzle-eligible chunks
  else if (g128 >= 8) g128 &= ~7;
  short8* Achunk = (short8*)(ws + o);
  int fullA = (g128 >= 256) ? 1 : 0;

  k_front    <<<B_N, 256, 0, stream>>>(cent, pred, feat, Bp, Achunk, fullA, scores, keys, s1, s2, cnt, besti);
  if (fullA) {
    k_mfma   <<<2048, 256, 0, stream>>>(Achunk, Bp, keys, 0);
  } else {
    for (int c0 = 0; c0 < 256; c0 += g128) {
      int g = (g128 < 256 - c0) ? g128 : (256 - c0);
      k_pack <<<g * 8, 256, 0, stream>>>(feat, Achunk, c0 * 8, B_N);
      k_mfma <<<g * 8, 256, 0, stream>>>(Achunk, Bp, keys, c0 * 128);
    }
  }
  k_post     <<<NCHUNK, 256, 0, stream>>>(keys, ui, labels, cosf_, s1, s2, cnt, besti, lrank, hist, out);
  k_prefix   <<<256, 256, 0, stream>>>(hist, base, class_n);
  k_sw       <<<B_N / 256, 256, 0, stream>>>(labels, lrank, base, scores, ui, cosf_, s1, s2, cnt, besti, lists_s, lists_u, out);
  k_replay   <<<250, 256, 0, stream>>>(ptn, lists_s, lists_u, class_n, labels, scores, ui, out);
}